// Round 13
// baseline (123.435 us; speedup 1.0000x reference)
//
#include <hip/hip_runtime.h>
#include <math.h>

#define DD   256
#define BB   1024
#define NEGN 64
#define S1N  25
#define S2N  10
#define OUTN 128
#define NB   (2 * BB + NEGN)    // 2112 output nodes
#define NREF1 (2 * BB * S2N + NEGN * S2N)   // 21120 i1 refs
#define NREF  (NREF1 + NB)                  // 23232 total self refs
#define NREFP 23280                         // padded to 291*80
#define TBLK 1250                           // transform blocks

typedef unsigned int  uint;
typedef unsigned short ushort;
typedef unsigned char uchar;
typedef short bf16x8 __attribute__((ext_vector_type(8)));
typedef float f32x4  __attribute__((ext_vector_type(4)));
typedef float f32x2  __attribute__((ext_vector_type(2)));

__device__ __forceinline__ ushort f2bf(float x) {
    uint u = __float_as_uint(x);
    u += 0x7FFFu + ((u >> 16) & 1u);     // RNE
    return (ushort)(u >> 16);
}
__device__ __forceinline__ float bflo(uint v) { return __uint_as_float(v << 16); }
__device__ __forceinline__ float bfhi(uint v) { return __uint_as_float(v & 0xFFFF0000u); }

// ---- fp8 e4m3 encode/decode (HW cvt with sw fallback); HI compile-time ----
#if __has_builtin(__builtin_amdgcn_cvt_pk_fp8_f32) && __has_builtin(__builtin_amdgcn_cvt_pk_f32_fp8)
__device__ __forceinline__ uchar fp8_enc(float x) {
    return (uchar)(__builtin_amdgcn_cvt_pk_fp8_f32(x, x, 0, false) & 0xff);
}
template <bool HI>
__device__ __forceinline__ f32x2 fp8_dec2(uint v) {
    return __builtin_amdgcn_cvt_pk_f32_fp8(v, HI);
}
#else
__device__ __forceinline__ uchar fp8_enc(float x) {
    uint u = __float_as_uint(x);
    uint s = (u >> 24) & 0x80u;
    float a = fabsf(x);
    if (a >= 448.f) return (uchar)(s | 0x7Eu);
    if (a < 0.0009765625f) return (uchar)s;
    int e; float fm = frexpf(a, &e);
    int pe = e - 1;
    uint code;
    if (pe >= -6) {
        int mi = (int)rintf((fm * 2.0f - 1.0f) * 8.0f);
        if (mi == 8) { mi = 0; pe += 1; }
        if (pe > 8) return (uchar)(s | 0x7Eu);
        code = ((uint)(pe + 7) << 3) | (uint)mi;
        if (code > 0x7Eu) code = 0x7Eu;
    } else {
        int mi = (int)rintf(a * 512.0f);
        code = (mi >= 8) ? 8u : (uint)mi;
    }
    return (uchar)(s | code);
}
__device__ __forceinline__ float fp8_dec1(uint b) {
    uint s = (b & 0x80u) << 24;
    uint em = b & 0x7fu;
    if (em >= 8) return __uint_as_float(s | ((em + 960u) << 20));
    float v = (float)em * 0.001953125f;
    return (b & 0x80u) ? -v : v;
}
template <bool HI>
__device__ __forceinline__ f32x2 fp8_dec2(uint v) {
    f32x2 r;
    uint w = HI ? (v >> 16) : v;
    r.x = fp8_dec1(w & 0xffu);
    r.y = fp8_dec1((w >> 8) & 0xffu);
    return r;
}
#endif

// ---- prep: Wt[col][k] = bf16(W[k][j]); col<128 -> Ws0, col>=128 -> Wn0 ----
__global__ __launch_bounds__(256)
void prep_w_k(const float* __restrict__ Ws0, const float* __restrict__ Wn0,
              ushort* __restrict__ Wt) {
    int col = blockIdx.x;
    int k   = threadIdx.x;
    const float* W = (col < OUTN) ? Ws0 : Wn0;
    int j = col & (OUTN - 1);
    Wt[(size_t)col * 256 + k] = f2bf(W[(size_t)k * OUTN + j]);
}

struct SegI {
    const int* i0[3];
    const int* i1[3];
    const int* i2[3];
};

__device__ __forceinline__ int map_ref(int r, const SegI& ix) {
    r = min(r, NREF - 1);
    if (r < 10240) return ix.i1[0][r];
    if (r < 20480) return ix.i1[1][r - 10240];
    if (r < 21120) return ix.i1[2][r - 20480];
    if (r < 22144) return ix.i0[0][r - 21120];
    if (r < 23168) return ix.i0[1][r - 22144];
    return ix.i0[2][r - 23168];
}

// cvt one float4 (16B of a row read by this lane) to uint2 of 4 bf16
__device__ __forceinline__ uint2 cvt4(float4 x) {
    uint2 r;
    r.x = (uint)f2bf(x.x) | ((uint)f2bf(x.y) << 16);
    r.y = (uint)f2bf(x.z) | ((uint)f2bf(x.w) << 16);
    return r;
}

// ---- merged: blocks [0,TBLK): yn8[n] = fp8(feat[n] @ Wn0) for all 200k nodes;
//              blocks [TBLK,TBLK+291): ysr[r] = bf16(feat[map_ref(r)] @ Ws0).
// Staging: lane l reads float4 at byte 16*l of one row -> each wave-instr is one
// fully-coalesced 1KB row. Wave w owns col-strip [32w,32w+32).
__global__ __launch_bounds__(256, 4)
void trans_ysg_k(const float* __restrict__ feat, const ushort* __restrict__ Wt,
                 SegI ix, uchar* __restrict__ yn8, ushort* __restrict__ ysr) {
    __shared__ ushort As[32 * 256];
    int w = threadIdx.x >> 6, l = threadIdx.x & 63;
    int lane16 = l & 15, kb = (l >> 4) * 8;

    if (blockIdx.x < TBLK) {
        // ---------------- transform_yn (fp8 out), 32-row tiles x5 ----------------
        int cbase = w * 32;
        bf16x8 bfr[2][8];
#pragma unroll
        for (int c = 0; c < 2; ++c) {
            int col = 128 + cbase + c * 16 + lane16;   // Wn0 half
#pragma unroll
            for (int kk = 0; kk < 8; ++kk)
                bfr[c][kk] = *(const bf16x8*)(Wt + (size_t)col * 256 + kk * 32 + kb);
        }

        uint2 wr[8];
        // prologue: stage tile 0 (wave w: rows 8w..8w+7, one row per instr)
#pragma unroll
        for (int i = 0; i < 8; ++i) {
            int r = w * 8 + i;
            wr[i] = cvt4(*(const float4*)(feat + ((size_t)blockIdx.x * 160 + r) * 256 + 4 * l));
        }

        for (int tile = 0; tile < 5; ++tile) {
            size_t orow = (size_t)blockIdx.x * 160 + tile * 32;
            __syncthreads();                    // prev tile's MFMA reads done
#pragma unroll
            for (int i = 0; i < 8; ++i) {
                int r = w * 8 + i;
                *(uint2*)&As[r * 256 + ((4 * l) ^ ((r & 7) << 3))] = wr[i];
            }
            __syncthreads();

            if (tile < 4) {
#pragma unroll
                for (int i = 0; i < 8; ++i) {
                    int r = w * 8 + i;
                    wr[i] = cvt4(*(const float4*)(feat + (orow + 32 + r) * 256 + 4 * l));
                }
            }

            f32x4 acc[2][2];
#pragma unroll
            for (int rf = 0; rf < 2; ++rf)
#pragma unroll
                for (int c = 0; c < 2; ++c)
#pragma unroll
                    for (int j = 0; j < 4; ++j) acc[rf][c][j] = 0.f;

#pragma unroll
            for (int kk = 0; kk < 8; ++kk) {
                int k0 = kk * 32 + kb;
#pragma unroll
                for (int rf = 0; rf < 2; ++rf) {
                    int arow = rf * 16 + lane16;
                    bf16x8 af = *(const bf16x8*)&As[arow * 256 + (k0 ^ ((arow & 7) << 3))];
#pragma unroll
                    for (int c = 0; c < 2; ++c)
                        acc[rf][c] = __builtin_amdgcn_mfma_f32_16x16x32_bf16(af, bfr[c][kk], acc[rf][c], 0, 0, 0);
                }
            }

#pragma unroll
            for (int rf = 0; rf < 2; ++rf) {
#pragma unroll
                for (int c = 0; c < 2; ++c) {
                    int col = cbase + c * 16 + lane16;
#pragma unroll
                    for (int j = 0; j < 4; ++j) {
                        size_t grow = orow + rf * 16 + (l >> 4) * 4 + j;
                        yn8[grow * 128 + col] = fp8_enc(acc[rf][c][j]);
                    }
                }
            }
        }
    } else {
        // ---------------- ysg (bf16 out), 16-row tiles x5, random rows ----------------
        int bid = blockIdx.x - TBLK;
        bf16x8 bfr[2][8];
#pragma unroll
        for (int c = 0; c < 2; ++c) {
            int col = w * 32 + c * 16 + lane16;   // Ws0 half
#pragma unroll
            for (int kk = 0; kk < 8; ++kk)
                bfr[c][kk] = *(const bf16x8*)(Wt + (size_t)col * 256 + kk * 32 + kb);
        }

        for (int tile = 0; tile < 5; ++tile) {
            int row0 = bid * 80 + tile * 16;
            uint2 wr[4];
#pragma unroll
            for (int i = 0; i < 4; ++i) {
                int src = map_ref(row0 + w * 4 + i, ix);
                wr[i] = cvt4(*(const float4*)(feat + (size_t)src * 256 + 4 * l));
            }
            __syncthreads();
#pragma unroll
            for (int i = 0; i < 4; ++i) {
                int r = w * 4 + i;
                *(uint2*)&As[r * 256 + ((4 * l) ^ ((r & 7) << 3))] = wr[i];
            }
            __syncthreads();

            f32x4 acc[2];
#pragma unroll
            for (int c = 0; c < 2; ++c)
#pragma unroll
                for (int j = 0; j < 4; ++j) acc[c][j] = 0.f;

#pragma unroll
            for (int kk = 0; kk < 8; ++kk) {
                int k0 = kk * 32 + kb;
                bf16x8 af = *(const bf16x8*)&As[lane16 * 256 + (k0 ^ ((lane16 & 7) << 3))];
#pragma unroll
                for (int c = 0; c < 2; ++c)
                    acc[c] = __builtin_amdgcn_mfma_f32_16x16x32_bf16(af, bfr[c][kk], acc[c], 0, 0, 0);
            }

#pragma unroll
            for (int c = 0; c < 2; ++c) {
                int col = w * 32 + c * 16 + lane16;
#pragma unroll
                for (int j = 0; j < 4; ++j) {
                    size_t grow = (size_t)row0 + (l >> 4) * 4 + j;
                    ysr[grow * 128 + col] = f2bf(acc[c][j]);
                }
            }
        }
    }
}

// ---- gather-all (R10-best): one BLOCK (5 waves) per node b; fp8 yn, 2 rows/load,
// wave-uniform indices in SGPRs via readlane. ----
__global__ __launch_bounds__(320)
void gather_all_k(const uint* __restrict__ ysrp, const uint* __restrict__ yn8u,
                  SegI ix, float* __restrict__ mg1, float* __restrict__ g0) {
    __shared__ float msL[5][64][2];
    __shared__ float mnL[5][32][4];
    __shared__ float gnL[5][32][4];
    int wv = threadIdx.x >> 6;   // 0..4
    int l  = threadIdx.x & 63;
    int b = blockIdx.x;

    int seg, lb;
    if (b < BB) { seg = 0; lb = b; }
    else if (b < 2 * BB) { seg = 1; lb = b - BB; }
    else { seg = 2; lb = b - 2 * BB; }
    const int sbase1[3] = {0, 10240, 20480};
    const int sbase0[3] = {21120, 22144, 23168};
    const int* p1 = ix.i1[seg];
    const int* p2 = ix.i2[seg];

    int i2v = (l < 50) ? p2[(size_t)lb * 250 + wv * 50 + l] : 0;
    int ia = p1[lb * S2N + 2 * wv];
    int ib = p1[lb * S2N + 2 * wv + 1];

    int half = l >> 5;           // which row of the pair this lane reads
    int cg   = l & 31;           // col group: cols 4cg..4cg+3

    float accA[4] = {0.f, 0.f, 0.f, 0.f};
    float accB[4] = {0.f, 0.f, 0.f, 0.f};
#pragma unroll
    for (int p = 0; p < 25; ++p) {
        int rlo = __builtin_amdgcn_readlane(i2v, 2 * p);
        int rhi = __builtin_amdgcn_readlane(i2v, 2 * p + 1);
        int ni = half ? rhi : rlo;
        uint v = yn8u[(size_t)ni * 32 + cg];
        f32x2 f01 = fp8_dec2<false>(v);
        f32x2 f23 = fp8_dec2<true>(v);
        if (p < 12) {
            accA[0] += f01.x; accA[1] += f01.y; accA[2] += f23.x; accA[3] += f23.y;
        } else if (p > 12) {
            accB[0] += f01.x; accB[1] += f01.y; accB[2] += f23.x; accB[3] += f23.y;
        } else {
            if (!half) { accA[0] += f01.x; accA[1] += f01.y; accA[2] += f23.x; accA[3] += f23.y; }
            else       { accB[0] += f01.x; accB[1] += f01.y; accB[2] += f23.x; accB[3] += f23.y; }
        }
    }
    float mnv[4], gnv[4];
    {
        int ng = half ? ib : ia;
        uint v = yn8u[(size_t)ng * 32 + cg];
        f32x2 f01 = fp8_dec2<false>(v);
        f32x2 f23 = fp8_dec2<true>(v);
        gnv[0] = f01.x; gnv[1] = f01.y; gnv[2] = f23.x; gnv[3] = f23.y;
    }
#pragma unroll
    for (int k = 0; k < 4; ++k) {
        accA[k] += __shfl_xor(accA[k], 32, 64);
        accB[k] += __shfl_xor(accB[k], 32, 64);
        gnv[k]  += __shfl_xor(gnv[k], 32, 64);
        mnv[k] = fmaxf(accA[k] * (1.0f / S1N), 0.f) + fmaxf(accB[k] * (1.0f / S1N), 0.f);
    }

    size_t refa = (size_t)(sbase1[seg] + lb * S2N + 2 * wv);
    uint sva = ysrp[refa * 64 + l];
    uint svb = ysrp[(refa + 1) * 64 + l];
    float ms0 = fmaxf(bflo(sva), 0.f) + fmaxf(bflo(svb), 0.f);
    float ms1 = fmaxf(bfhi(sva), 0.f) + fmaxf(bfhi(svb), 0.f);

    msL[wv][l][0] = ms0; msL[wv][l][1] = ms1;
    if (l < 32) {
#pragma unroll
        for (int k = 0; k < 4; ++k) { mnL[wv][l][k] = mnv[k]; gnL[wv][l][k] = gnv[k]; }
    }
    __syncthreads();

    int g = threadIdx.x >> 6, c = l;
    const float invS2 = 1.0f / S2N;
    if (g == 0) {
        float s0 = 0.f, s1 = 0.f;
#pragma unroll
        for (int w2 = 0; w2 < 5; ++w2) { s0 += msL[w2][c][0]; s1 += msL[w2][c][1]; }
        float2 o; o.x = s0 * invS2; o.y = s1 * invS2;
        *(float2*)(mg1 + (size_t)b * DD + 2 * c) = o;
    } else if (g == 1) {
        if (c < 32) {
            float4 o;
            float s[4] = {0.f, 0.f, 0.f, 0.f};
#pragma unroll
            for (int w2 = 0; w2 < 5; ++w2)
#pragma unroll
                for (int k = 0; k < 4; ++k) s[k] += mnL[w2][c][k];
            o.x = s[0] * invS2; o.y = s[1] * invS2; o.z = s[2] * invS2; o.w = s[3] * invS2;
            *(float4*)(mg1 + (size_t)b * DD + 128 + 4 * c) = o;
        }
    } else if (g == 2) {
        if (c < 32) {
            float4 o;
            float s[4] = {0.f, 0.f, 0.f, 0.f};
#pragma unroll
            for (int w2 = 0; w2 < 5; ++w2)
#pragma unroll
                for (int k = 0; k < 4; ++k) s[k] += gnL[w2][c][k];
            o.x = fmaxf(s[0] * invS2, 0.f); o.y = fmaxf(s[1] * invS2, 0.f);
            o.z = fmaxf(s[2] * invS2, 0.f); o.w = fmaxf(s[3] * invS2, 0.f);
            *(float4*)(g0 + (size_t)b * DD + 128 + 4 * c) = o;
        }
    } else if (g == 3) {
        uint v = ysrp[(size_t)(sbase0[seg] + lb) * 64 + c];
        float2 o; o.x = fmaxf(bflo(v), 0.f); o.y = fmaxf(bfhi(v), 0.f);
        *(float2*)(g0 + (size_t)b * DD + 2 * c) = o;
    }
}

// ---- final layer: [g0 | mg1] @ [Ws1;Wn1] + L2 norm; 8 rows/block; zeroes loss ----
__global__ __launch_bounds__(256)
void final_fused_k(const float* __restrict__ g0, const float* __restrict__ mg1,
                   const float* __restrict__ Ws, const float* __restrict__ Wn,
                   float* __restrict__ u1, float* __restrict__ u2,
                   float* __restrict__ un, float* __restrict__ loss) {
    constexpr int R = 8;
    __shared__ float xsS[R][DD];
    __shared__ float xnS[R][DD];
    __shared__ float nrmS[R];
    if (blockIdx.x == 0 && threadIdx.x == 0) loss[0] = 0.f;
    int r0 = blockIdx.x * R;
    int wv = threadIdx.x >> 6;
    int c  = threadIdx.x & 63;

#pragma unroll
    for (int rr = 0; rr < R / 4; ++rr) {
        int r = wv * (R / 4) + rr;
        int row = r0 + r;
        *(float4*)&xsS[r][c * 4] = *(const float4*)(g0 + (size_t)row * DD + c * 4);
        *(float4*)&xnS[r][c * 4] = *(const float4*)(mg1 + (size_t)row * DD + c * 4);
    }
    __syncthreads();

    int j = threadIdx.x & (OUTN - 1);
    const float* Wj = ((threadIdx.x < OUTN) ? Ws : Wn) + j;
    const float (*X)[DD] = (threadIdx.x < OUTN) ? xsS : xnS;
    float acc[R];
#pragma unroll
    for (int r = 0; r < R; ++r) acc[r] = 0.f;
#pragma unroll 4
    for (int k4 = 0; k4 < DD; k4 += 4) {
        float w0 = Wj[(k4 + 0) * OUTN];
        float w1 = Wj[(k4 + 1) * OUTN];
        float w2 = Wj[(k4 + 2) * OUTN];
        float w3 = Wj[(k4 + 3) * OUTN];
#pragma unroll
        for (int r = 0; r < R; ++r) {
            float4 x = *(const float4*)&X[r][k4];
            acc[r] = fmaf(x.x, w0, acc[r]);
            acc[r] = fmaf(x.y, w1, acc[r]);
            acc[r] = fmaf(x.z, w2, acc[r]);
            acc[r] = fmaf(x.w, w3, acc[r]);
        }
    }
    __syncthreads();
    float* sq = &xsS[0][0];
#pragma unroll
    for (int r = 0; r < R; ++r) sq[r * DD + threadIdx.x] = acc[r] * acc[r];
    __syncthreads();
    {
        int g = threadIdx.x >> 5, ll = threadIdx.x & 31;
        float s = 0.f;
#pragma unroll
        for (int i = 0; i < 8; ++i) s += sq[g * DD + ll + 32 * i];
        s += __shfl_down(s, 16, 64);
        s += __shfl_down(s, 8, 64);
        s += __shfl_down(s, 4, 64);
        s += __shfl_down(s, 2, 64);
        s += __shfl_down(s, 1, 64);
        if (ll == 0) nrmS[g] = fmaxf(sqrtf(s), 1e-12f);
    }
    __syncthreads();
#pragma unroll
    for (int r = 0; r < R; ++r) {
        int row = r0 + r;
        float* dst;
        if (row < BB) dst = u1 + (size_t)row * DD;
        else if (row < 2 * BB) dst = u2 + (size_t)(row - BB) * DD;
        else dst = un + (size_t)(row - 2 * BB) * DD;
        dst[threadIdx.x] = acc[r] / nrmS[r];
    }
}

__device__ __forceinline__ float softplus_f(float x) {
    return fmaxf(x, 0.f) + log1pf(expf(-fabsf(x)));
}

// per-b: aff[b], neg[b][:], and atomicAdd of this block's loss share
__global__ __launch_bounds__(256)
void aff_neg_k(const float* __restrict__ u1, const float* __restrict__ u2,
               const float* __restrict__ un, float* __restrict__ aff,
               float* __restrict__ neg, float* __restrict__ loss) {
    __shared__ float u1s[DD];
    __shared__ float red[256];
    int b = blockIdx.x, t = threadIdx.x;
    float av = u1[(size_t)b * DD + t];
    u1s[t] = av;
    red[t] = av * u2[(size_t)b * DD + t];
    __syncthreads();
    for (int s = 128; s > 0; s >>= 1) { if (t < s) red[t] += red[t + s]; __syncthreads(); }
    float affv = red[0];
    __syncthreads();
    if (t == 0) aff[b] = affv;

    int j = t >> 2, q = t & 3;
    float acc = 0.f;
    const float* up = un + (size_t)j * DD + q * 64;
    const float* us = u1s + q * 64;
#pragma unroll
    for (int i = 0; i < 16; ++i) {
        float4 x = *(const float4*)(up + 4 * i);
        float4 y = *(const float4*)(us + 4 * i);
        acc = fmaf(x.x, y.x, acc); acc = fmaf(x.y, y.y, acc);
        acc = fmaf(x.z, y.z, acc); acc = fmaf(x.w, y.w, acc);
    }
    acc += __shfl_down(acc, 2, 64);
    acc += __shfl_down(acc, 1, 64);
    float sp = 0.f;
    if (q == 0) {
        neg[(size_t)b * NEGN + j] = acc;
        sp = softplus_f(acc);
    }
    if (t == 0) sp += softplus_f(-affv);
    red[t] = sp;
    __syncthreads();
    for (int s = 128; s > 0; s >>= 1) { if (t < s) red[t] += red[t + s]; __syncthreads(); }
    if (t == 0) atomicAdd(loss, red[0] * (1.0f / BB));
}

extern "C" void kernel_launch(void* const* d_in, const int* in_sizes, int n_in,
                              void* d_out, int out_size, void* d_ws, size_t ws_size,
                              hipStream_t stream) {
    const float* feat = (const float*)d_in[0];
    const float* Ws0  = (const float*)d_in[1];
    const float* Wn0  = (const float*)d_in[2];
    const float* Ws1  = (const float*)d_in[3];
    const float* Wn1  = (const float*)d_in[4];
    const int* s1_0 = (const int*)d_in[5];
    const int* s1_1 = (const int*)d_in[6];
    const int* s1_2 = (const int*)d_in[7];
    const int* s2_0 = (const int*)d_in[8];
    const int* s2_1 = (const int*)d_in[9];
    const int* s2_2 = (const int*)d_in[10];
    const int* n_0  = (const int*)d_in[11];
    const int* n_1  = (const int*)d_in[12];
    const int* n_2  = (const int*)d_in[13];

    float* out  = (float*)d_out;
    float* loss = out;
    float* aff  = out + 1;
    float* neg  = out + 1 + BB;
    float* u1   = out + 1 + BB + BB * NEGN;

    char* wsb = (char*)d_ws;
    size_t off = 0;
    ushort* Wt  = (ushort*)(wsb + off); off += (size_t)256 * 256 * 2;
    uchar*  yn8 = (uchar*)(wsb + off);  off += (size_t)200000 * 128;
    ushort* ysr = (ushort*)(wsb + off); off += (size_t)NREFP * 128 * 2;
    float* mg1  = (float*)(wsb + off); off += (size_t)NB * DD * 4;
    float* g0   = (float*)(wsb + off); off += (size_t)NB * DD * 4;
    float* u2   = (float*)(wsb + off); off += (size_t)BB * DD * 4;
    float* un   = (float*)(wsb + off); off += (size_t)NEGN * DD * 4;

    SegI ix;
    ix.i0[0] = s1_0; ix.i0[1] = s2_0; ix.i0[2] = n_0;
    ix.i1[0] = s1_1; ix.i1[1] = s2_1; ix.i1[2] = n_1;
    ix.i2[0] = s1_2; ix.i2[1] = s2_2; ix.i2[2] = n_2;

    prep_w_k<<<256, 256, 0, stream>>>(Ws0, Wn0, Wt);
    trans_ysg_k<<<TBLK + 291, 256, 0, stream>>>(feat, Wt, ix, yn8, ysr);

    gather_all_k<<<NB, 320, 0, stream>>>((const uint*)ysr, (const uint*)yn8, ix, mg1, g0);

    final_fused_k<<<NB / 8, 256, 0, stream>>>(g0, mg1, Ws1, Wn1, u1, u2, un, loss);

    aff_neg_k<<<BB, 256, 0, stream>>>(u1, u2, un, aff, neg, loss);
}

// Round 14
// 108.644 us; speedup vs baseline: 1.1361x; 1.1361x over previous
//
#include <hip/hip_runtime.h>
#include <math.h>

#define DD   256
#define BB   1024
#define NEGN 64
#define S1N  25
#define S2N  10
#define OUTN 128
#define NB   (2 * BB + NEGN)    // 2112 output nodes
#define NREF1 (2 * BB * S2N + NEGN * S2N)   // 21120 i1 refs
#define NREF  (NREF1 + NB)                  // 23232 total self refs
#define NREFP 23280                         // padded to 291*80
#define TBLK 1250                           // transform blocks

typedef unsigned int  uint;
typedef unsigned short ushort;
typedef unsigned char uchar;
typedef short bf16x8 __attribute__((ext_vector_type(8)));
typedef float f32x4  __attribute__((ext_vector_type(4)));
typedef float f32x2  __attribute__((ext_vector_type(2)));

__device__ __forceinline__ ushort f2bf(float x) {
    uint u = __float_as_uint(x);
    u += 0x7FFFu + ((u >> 16) & 1u);     // RNE
    return (ushort)(u >> 16);
}
__device__ __forceinline__ float bflo(uint v) { return __uint_as_float(v << 16); }
__device__ __forceinline__ float bfhi(uint v) { return __uint_as_float(v & 0xFFFF0000u); }

// ---- fp8 e4m3 encode/decode (HW cvt with sw fallback); HI compile-time ----
#if __has_builtin(__builtin_amdgcn_cvt_pk_fp8_f32) && __has_builtin(__builtin_amdgcn_cvt_pk_f32_fp8)
__device__ __forceinline__ uchar fp8_enc(float x) {
    return (uchar)(__builtin_amdgcn_cvt_pk_fp8_f32(x, x, 0, false) & 0xff);
}
template <bool HI>
__device__ __forceinline__ f32x2 fp8_dec2(uint v) {
    return __builtin_amdgcn_cvt_pk_f32_fp8(v, HI);
}
#else
__device__ __forceinline__ uchar fp8_enc(float x) {
    uint u = __float_as_uint(x);
    uint s = (u >> 24) & 0x80u;
    float a = fabsf(x);
    if (a >= 448.f) return (uchar)(s | 0x7Eu);
    if (a < 0.0009765625f) return (uchar)s;
    int e; float fm = frexpf(a, &e);
    int pe = e - 1;
    uint code;
    if (pe >= -6) {
        int mi = (int)rintf((fm * 2.0f - 1.0f) * 8.0f);
        if (mi == 8) { mi = 0; pe += 1; }
        if (pe > 8) return (uchar)(s | 0x7Eu);
        code = ((uint)(pe + 7) << 3) | (uint)mi;
        if (code > 0x7Eu) code = 0x7Eu;
    } else {
        int mi = (int)rintf(a * 512.0f);
        code = (mi >= 8) ? 8u : (uint)mi;
    }
    return (uchar)(s | code);
}
__device__ __forceinline__ float fp8_dec1(uint b) {
    uint s = (b & 0x80u) << 24;
    uint em = b & 0x7fu;
    if (em >= 8) return __uint_as_float(s | ((em + 960u) << 20));
    float v = (float)em * 0.001953125f;
    return (b & 0x80u) ? -v : v;
}
template <bool HI>
__device__ __forceinline__ f32x2 fp8_dec2(uint v) {
    f32x2 r;
    uint w = HI ? (v >> 16) : v;
    r.x = fp8_dec1(w & 0xffu);
    r.y = fp8_dec1((w >> 8) & 0xffu);
    return r;
}
#endif

// ---- prep: Wt[col][k] = bf16(W[k][j]); col<128 -> Ws0, col>=128 -> Wn0 ----
__global__ __launch_bounds__(256)
void prep_w_k(const float* __restrict__ Ws0, const float* __restrict__ Wn0,
              ushort* __restrict__ Wt) {
    int col = blockIdx.x;
    int k   = threadIdx.x;
    const float* W = (col < OUTN) ? Ws0 : Wn0;
    int j = col & (OUTN - 1);
    Wt[(size_t)col * 256 + k] = f2bf(W[(size_t)k * OUTN + j]);
}

struct SegI {
    const int* i0[3];
    const int* i1[3];
    const int* i2[3];
};

__device__ __forceinline__ int map_ref(int r, const SegI& ix) {
    r = min(r, NREF - 1);
    if (r < 10240) return ix.i1[0][r];
    if (r < 20480) return ix.i1[1][r - 10240];
    if (r < 21120) return ix.i1[2][r - 20480];
    if (r < 22144) return ix.i0[0][r - 21120];
    if (r < 23168) return ix.i0[1][r - 22144];
    return ix.i0[2][r - 23168];
}

// ---- merged: blocks [0,TBLK): yn8[n] = fp8(feat[n] @ Wn0) for all 200k nodes;
//              blocks [TBLK,TBLK+291): ysr[r] = bf16(feat[map_ref(r)] @ Ws0).
// yn path: wave w owns col-strip [32w,32w+32), all 32 rows; reg prefetch.
__global__ __launch_bounds__(256, 4)
void trans_ysg_k(const float* __restrict__ feat, const ushort* __restrict__ Wt,
                 SegI ix, uchar* __restrict__ yn8, ushort* __restrict__ ysr) {
    __shared__ ushort As[32 * 256];
    int w = threadIdx.x >> 6, l = threadIdx.x & 63;
    int lane16 = l & 15, kb = (l >> 4) * 8;

    if (blockIdx.x < TBLK) {
        int cbase = w * 32;
        bf16x8 bfr[2][8];
#pragma unroll
        for (int c = 0; c < 2; ++c) {
            int col = 128 + cbase + c * 16 + lane16;   // Wn0 half
#pragma unroll
            for (int kk = 0; kk < 8; ++kk)
                bfr[c][kk] = *(const bf16x8*)(Wt + (size_t)col * 256 + kk * 32 + kb);
        }
        int rr = threadIdx.x >> 4;
        int cq = threadIdx.x & 15;

        uint2 wr[2][4];
#pragma unroll
        for (int hf = 0; hf < 2; ++hf) {
            int r = hf * 16 + rr;
#pragma unroll
            for (int q = 0; q < 4; ++q) {
                float4 x = *(const float4*)(feat + ((size_t)blockIdx.x * 160 + r) * 256 + cq * 16 + q * 4);
                wr[hf][q].x = (uint)f2bf(x.x) | ((uint)f2bf(x.y) << 16);
                wr[hf][q].y = (uint)f2bf(x.z) | ((uint)f2bf(x.w) << 16);
            }
        }

        for (int tile = 0; tile < 5; ++tile) {
            size_t orow = (size_t)blockIdx.x * 160 + tile * 32;
            __syncthreads();
#pragma unroll
            for (int hf = 0; hf < 2; ++hf) {
                int r = hf * 16 + rr;
#pragma unroll
                for (int q = 0; q < 4; ++q) {
                    int col = cq * 16 + q * 4;
                    *(uint2*)&As[r * 256 + (col ^ ((r & 7) << 3))] = wr[hf][q];
                }
            }
            __syncthreads();

            if (tile < 4) {
#pragma unroll
                for (int hf = 0; hf < 2; ++hf) {
                    int r = hf * 16 + rr;
#pragma unroll
                    for (int q = 0; q < 4; ++q) {
                        float4 x = *(const float4*)(feat + (orow + 32 + r) * 256 + cq * 16 + q * 4);
                        wr[hf][q].x = (uint)f2bf(x.x) | ((uint)f2bf(x.y) << 16);
                        wr[hf][q].y = (uint)f2bf(x.z) | ((uint)f2bf(x.w) << 16);
                    }
                }
            }

            f32x4 acc[2][2];
#pragma unroll
            for (int rf = 0; rf < 2; ++rf)
#pragma unroll
                for (int c = 0; c < 2; ++c)
#pragma unroll
                    for (int j = 0; j < 4; ++j) acc[rf][c][j] = 0.f;

#pragma unroll
            for (int kk = 0; kk < 8; ++kk) {
                int k0 = kk * 32 + kb;
#pragma unroll
                for (int rf = 0; rf < 2; ++rf) {
                    int arow = rf * 16 + lane16;
                    bf16x8 af = *(const bf16x8*)&As[arow * 256 + (k0 ^ ((arow & 7) << 3))];
#pragma unroll
                    for (int c = 0; c < 2; ++c)
                        acc[rf][c] = __builtin_amdgcn_mfma_f32_16x16x32_bf16(af, bfr[c][kk], acc[rf][c], 0, 0, 0);
                }
            }

#pragma unroll
            for (int rf = 0; rf < 2; ++rf) {
#pragma unroll
                for (int c = 0; c < 2; ++c) {
                    int col = cbase + c * 16 + lane16;
#pragma unroll
                    for (int j = 0; j < 4; ++j) {
                        size_t grow = orow + rf * 16 + (l >> 4) * 4 + j;
                        yn8[grow * 128 + col] = fp8_enc(acc[rf][c][j]);
                    }
                }
            }
        }
    } else {
        int bid = blockIdx.x - TBLK;
        bf16x8 bfr[2][8];
#pragma unroll
        for (int c = 0; c < 2; ++c) {
            int col = w * 32 + c * 16 + lane16;   // Ws0 half
#pragma unroll
            for (int kk = 0; kk < 8; ++kk)
                bfr[c][kk] = *(const bf16x8*)(Wt + (size_t)col * 256 + kk * 32 + kb);
        }
        int rr = threadIdx.x >> 4;
        int cq = threadIdx.x & 15;

        for (int tile = 0; tile < 5; ++tile) {
            int row0 = bid * 80 + tile * 16;
            int src = map_ref(row0 + rr, ix);
            uint2 wr[4];
#pragma unroll
            for (int q = 0; q < 4; ++q) {
                float4 x = *(const float4*)(feat + (size_t)src * 256 + cq * 16 + q * 4);
                wr[q].x = (uint)f2bf(x.x) | ((uint)f2bf(x.y) << 16);
                wr[q].y = (uint)f2bf(x.z) | ((uint)f2bf(x.w) << 16);
            }
            __syncthreads();
#pragma unroll
            for (int q = 0; q < 4; ++q) {
                int col = cq * 16 + q * 4;
                *(uint2*)&As[rr * 256 + (col ^ ((rr & 7) << 3))] = wr[q];
            }
            __syncthreads();

            f32x4 acc[2];
#pragma unroll
            for (int c = 0; c < 2; ++c)
#pragma unroll
                for (int j = 0; j < 4; ++j) acc[c][j] = 0.f;

#pragma unroll
            for (int kk = 0; kk < 8; ++kk) {
                int k0 = kk * 32 + kb;
                bf16x8 af = *(const bf16x8*)&As[lane16 * 256 + (k0 ^ ((lane16 & 7) << 3))];
#pragma unroll
                for (int c = 0; c < 2; ++c)
                    acc[c] = __builtin_amdgcn_mfma_f32_16x16x32_bf16(af, bfr[c][kk], acc[c], 0, 0, 0);
            }

#pragma unroll
            for (int c = 0; c < 2; ++c) {
                int col = w * 32 + c * 16 + lane16;
#pragma unroll
                for (int j = 0; j < 4; ++j) {
                    size_t grow = (size_t)row0 + (l >> 4) * 4 + j;
                    ysr[grow * 128 + col] = f2bf(acc[c][j]);
                }
            }
        }
    }
}

// ---- gather-all: one BLOCK (5 waves) per output node b; fp8 yn, 2 rows/load.
__global__ __launch_bounds__(320)
void gather_all_k(const uint* __restrict__ ysrp, const uint* __restrict__ yn8u,
                  SegI ix, float* __restrict__ mg1, float* __restrict__ g0) {
    __shared__ float msL[5][64][2];
    __shared__ float mnL[5][32][4];
    __shared__ float gnL[5][32][4];
    int wv = threadIdx.x >> 6;   // 0..4
    int l  = threadIdx.x & 63;
    int b = blockIdx.x;

    int seg, lb;
    if (b < BB) { seg = 0; lb = b; }
    else if (b < 2 * BB) { seg = 1; lb = b - BB; }
    else { seg = 2; lb = b - 2 * BB; }
    const int sbase1[3] = {0, 10240, 20480};
    const int sbase0[3] = {21120, 22144, 23168};
    const int* p1 = ix.i1[seg];
    const int* p2 = ix.i2[seg];

    int i2v = (l < 50) ? p2[(size_t)lb * 250 + wv * 50 + l] : 0;
    int ia = p1[lb * S2N + 2 * wv];
    int ib = p1[lb * S2N + 2 * wv + 1];

    int half = l >> 5;           // which row of the pair this lane reads
    int cg   = l & 31;           // col group: cols 4cg..4cg+3

    float accA[4] = {0.f, 0.f, 0.f, 0.f};
    float accB[4] = {0.f, 0.f, 0.f, 0.f};
#pragma unroll
    for (int p = 0; p < 25; ++p) {
        int rlo = __builtin_amdgcn_readlane(i2v, 2 * p);
        int rhi = __builtin_amdgcn_readlane(i2v, 2 * p + 1);
        int ni = half ? rhi : rlo;
        uint v = yn8u[(size_t)ni * 32 + cg];
        f32x2 f01 = fp8_dec2<false>(v);
        f32x2 f23 = fp8_dec2<true>(v);
        if (p < 12) {
            accA[0] += f01.x; accA[1] += f01.y; accA[2] += f23.x; accA[3] += f23.y;
        } else if (p > 12) {
            accB[0] += f01.x; accB[1] += f01.y; accB[2] += f23.x; accB[3] += f23.y;
        } else {
            if (!half) { accA[0] += f01.x; accA[1] += f01.y; accA[2] += f23.x; accA[3] += f23.y; }
            else       { accB[0] += f01.x; accB[1] += f01.y; accB[2] += f23.x; accB[3] += f23.y; }
        }
    }
    float mnv[4], gnv[4];
    {
        int ng = half ? ib : ia;
        uint v = yn8u[(size_t)ng * 32 + cg];
        f32x2 f01 = fp8_dec2<false>(v);
        f32x2 f23 = fp8_dec2<true>(v);
        gnv[0] = f01.x; gnv[1] = f01.y; gnv[2] = f23.x; gnv[3] = f23.y;
    }
#pragma unroll
    for (int k = 0; k < 4; ++k) {
        accA[k] += __shfl_xor(accA[k], 32, 64);
        accB[k] += __shfl_xor(accB[k], 32, 64);
        gnv[k]  += __shfl_xor(gnv[k], 32, 64);
        mnv[k] = fmaxf(accA[k] * (1.0f / S1N), 0.f) + fmaxf(accB[k] * (1.0f / S1N), 0.f);
    }

    size_t refa = (size_t)(sbase1[seg] + lb * S2N + 2 * wv);
    uint sva = ysrp[refa * 64 + l];
    uint svb = ysrp[(refa + 1) * 64 + l];
    float ms0 = fmaxf(bflo(sva), 0.f) + fmaxf(bflo(svb), 0.f);
    float ms1 = fmaxf(bfhi(sva), 0.f) + fmaxf(bfhi(svb), 0.f);

    msL[wv][l][0] = ms0; msL[wv][l][1] = ms1;
    if (l < 32) {
#pragma unroll
        for (int k = 0; k < 4; ++k) { mnL[wv][l][k] = mnv[k]; gnL[wv][l][k] = gnv[k]; }
    }
    __syncthreads();

    int g = threadIdx.x >> 6, c = l;
    const float invS2 = 1.0f / S2N;
    if (g == 0) {
        float s0 = 0.f, s1 = 0.f;
#pragma unroll
        for (int w2 = 0; w2 < 5; ++w2) { s0 += msL[w2][c][0]; s1 += msL[w2][c][1]; }
        float2 o; o.x = s0 * invS2; o.y = s1 * invS2;
        *(float2*)(mg1 + (size_t)b * DD + 2 * c) = o;
    } else if (g == 1) {
        if (c < 32) {
            float4 o;
            float s[4] = {0.f, 0.f, 0.f, 0.f};
#pragma unroll
            for (int w2 = 0; w2 < 5; ++w2)
#pragma unroll
                for (int k = 0; k < 4; ++k) s[k] += mnL[w2][c][k];
            o.x = s[0] * invS2; o.y = s[1] * invS2; o.z = s[2] * invS2; o.w = s[3] * invS2;
            *(float4*)(mg1 + (size_t)b * DD + 128 + 4 * c) = o;
        }
    } else if (g == 2) {
        if (c < 32) {
            float4 o;
            float s[4] = {0.f, 0.f, 0.f, 0.f};
#pragma unroll
            for (int w2 = 0; w2 < 5; ++w2)
#pragma unroll
                for (int k = 0; k < 4; ++k) s[k] += gnL[w2][c][k];
            o.x = fmaxf(s[0] * invS2, 0.f); o.y = fmaxf(s[1] * invS2, 0.f);
            o.z = fmaxf(s[2] * invS2, 0.f); o.w = fmaxf(s[3] * invS2, 0.f);
            *(float4*)(g0 + (size_t)b * DD + 128 + 4 * c) = o;
        }
    } else if (g == 3) {
        uint v = ysrp[(size_t)(sbase0[seg] + lb) * 64 + c];
        float2 o; o.x = fmaxf(bflo(v), 0.f); o.y = fmaxf(bfhi(v), 0.f);
        *(float2*)(g0 + (size_t)b * DD + 2 * c) = o;
    }
}

// ---- final layer: [g0 | mg1] @ [Ws1;Wn1] + L2 norm; 8 rows/block ----
__global__ __launch_bounds__(256)
void final_fused_k(const float* __restrict__ g0, const float* __restrict__ mg1,
                   const float* __restrict__ Ws, const float* __restrict__ Wn,
                   float* __restrict__ u1, float* __restrict__ u2,
                   float* __restrict__ un) {
    constexpr int R = 8;
    __shared__ float xsS[R][DD];
    __shared__ float xnS[R][DD];
    __shared__ float nrmS[R];
    int r0 = blockIdx.x * R;
    int wv = threadIdx.x >> 6;
    int c  = threadIdx.x & 63;

#pragma unroll
    for (int rr = 0; rr < R / 4; ++rr) {
        int r = wv * (R / 4) + rr;
        int row = r0 + r;
        *(float4*)&xsS[r][c * 4] = *(const float4*)(g0 + (size_t)row * DD + c * 4);
        *(float4*)&xnS[r][c * 4] = *(const float4*)(mg1 + (size_t)row * DD + c * 4);
    }
    __syncthreads();

    int j = threadIdx.x & (OUTN - 1);
    const float* Wj = ((threadIdx.x < OUTN) ? Ws : Wn) + j;
    const float (*X)[DD] = (threadIdx.x < OUTN) ? xsS : xnS;
    float acc[R];
#pragma unroll
    for (int r = 0; r < R; ++r) acc[r] = 0.f;
#pragma unroll 4
    for (int k4 = 0; k4 < DD; k4 += 4) {
        float w0 = Wj[(k4 + 0) * OUTN];
        float w1 = Wj[(k4 + 1) * OUTN];
        float w2 = Wj[(k4 + 2) * OUTN];
        float w3 = Wj[(k4 + 3) * OUTN];
#pragma unroll
        for (int r = 0; r < R; ++r) {
            float4 x = *(const float4*)&X[r][k4];
            acc[r] = fmaf(x.x, w0, acc[r]);
            acc[r] = fmaf(x.y, w1, acc[r]);
            acc[r] = fmaf(x.z, w2, acc[r]);
            acc[r] = fmaf(x.w, w3, acc[r]);
        }
    }
    __syncthreads();
    float* sq = &xsS[0][0];
#pragma unroll
    for (int r = 0; r < R; ++r) sq[r * DD + threadIdx.x] = acc[r] * acc[r];
    __syncthreads();
    {
        int g = threadIdx.x >> 5, ll = threadIdx.x & 31;
        float s = 0.f;
#pragma unroll
        for (int i = 0; i < 8; ++i) s += sq[g * DD + ll + 32 * i];
        s += __shfl_down(s, 16, 64);
        s += __shfl_down(s, 8, 64);
        s += __shfl_down(s, 4, 64);
        s += __shfl_down(s, 2, 64);
        s += __shfl_down(s, 1, 64);
        if (ll == 0) nrmS[g] = fmaxf(sqrtf(s), 1e-12f);
    }
    __syncthreads();
#pragma unroll
    for (int r = 0; r < R; ++r) {
        int row = r0 + r;
        float* dst;
        if (row < BB) dst = u1 + (size_t)row * DD;
        else if (row < 2 * BB) dst = u2 + (size_t)(row - BB) * DD;
        else dst = un + (size_t)(row - 2 * BB) * DD;
        dst[threadIdx.x] = acc[r] / nrmS[r];
    }
}

__device__ __forceinline__ float softplus_f(float x) {
    return fmaxf(x, 0.f) + log1pf(expf(-fabsf(x)));
}

// per-b: aff[b], neg[b][0..63], and partial loss contribution part[b]
__global__ __launch_bounds__(256)
void aff_neg_k(const float* __restrict__ u1, const float* __restrict__ u2,
               const float* __restrict__ un, float* __restrict__ aff,
               float* __restrict__ neg, float* __restrict__ part) {
    __shared__ float u1s[DD];
    __shared__ float red[256];
    int b = blockIdx.x, t = threadIdx.x;
    float av = u1[(size_t)b * DD + t];
    u1s[t] = av;
    red[t] = av * u2[(size_t)b * DD + t];
    __syncthreads();
    for (int s = 128; s > 0; s >>= 1) { if (t < s) red[t] += red[t + s]; __syncthreads(); }
    float affv = red[0];
    __syncthreads();
    if (t == 0) aff[b] = affv;

    int j = t >> 2, q = t & 3;
    float acc = 0.f;
    const float* up = un + (size_t)j * DD + q * 64;
    const float* us = u1s + q * 64;
#pragma unroll
    for (int i = 0; i < 16; ++i) {
        float4 x = *(const float4*)(up + 4 * i);
        float4 y = *(const float4*)(us + 4 * i);
        acc = fmaf(x.x, y.x, acc); acc = fmaf(x.y, y.y, acc);
        acc = fmaf(x.z, y.z, acc); acc = fmaf(x.w, y.w, acc);
    }
    acc += __shfl_down(acc, 2, 64);
    acc += __shfl_down(acc, 1, 64);
    float sp = 0.f;
    if (q == 0) {
        neg[(size_t)b * NEGN + j] = acc;
        sp = softplus_f(acc);
    }
    if (t == 0) sp += softplus_f(-affv);
    red[t] = sp;
    __syncthreads();
    for (int s = 128; s > 0; s >>= 1) { if (t < s) red[t] += red[t + s]; __syncthreads(); }
    if (t == 0) part[b] = red[0];
}

__global__ __launch_bounds__(256)
void loss_final_k(const float* __restrict__ part, float* __restrict__ loss) {
    __shared__ float red[256];
    int t = threadIdx.x;
    red[t] = part[t] + part[t + 256] + part[t + 512] + part[t + 768];
    __syncthreads();
    for (int s = 128; s > 0; s >>= 1) { if (t < s) red[t] += red[t + s]; __syncthreads(); }
    if (t == 0) loss[0] = red[0] / (float)BB;
}

extern "C" void kernel_launch(void* const* d_in, const int* in_sizes, int n_in,
                              void* d_out, int out_size, void* d_ws, size_t ws_size,
                              hipStream_t stream) {
    const float* feat = (const float*)d_in[0];
    const float* Ws0  = (const float*)d_in[1];
    const float* Wn0  = (const float*)d_in[2];
    const float* Ws1  = (const float*)d_in[3];
    const float* Wn1  = (const float*)d_in[4];
    const int* s1_0 = (const int*)d_in[5];
    const int* s1_1 = (const int*)d_in[6];
    const int* s1_2 = (const int*)d_in[7];
    const int* s2_0 = (const int*)d_in[8];
    const int* s2_1 = (const int*)d_in[9];
    const int* s2_2 = (const int*)d_in[10];
    const int* n_0  = (const int*)d_in[11];
    const int* n_1  = (const int*)d_in[12];
    const int* n_2  = (const int*)d_in[13];

    float* out  = (float*)d_out;
    float* loss = out;
    float* aff  = out + 1;
    float* neg  = out + 1 + BB;
    float* u1   = out + 1 + BB + BB * NEGN;

    char* wsb = (char*)d_ws;
    size_t off = 0;
    ushort* Wt  = (ushort*)(wsb + off); off += (size_t)256 * 256 * 2;
    uchar*  yn8 = (uchar*)(wsb + off);  off += (size_t)200000 * 128;
    ushort* ysr = (ushort*)(wsb + off); off += (size_t)NREFP * 128 * 2;
    float* mg1  = (float*)(wsb + off); off += (size_t)NB * DD * 4;
    float* g0   = (float*)(wsb + off); off += (size_t)NB * DD * 4;
    float* u2   = (float*)(wsb + off); off += (size_t)BB * DD * 4;
    float* un   = (float*)(wsb + off); off += (size_t)NEGN * DD * 4;
    float* part = (float*)(wsb + off); off += (size_t)BB * 4;

    SegI ix;
    ix.i0[0] = s1_0; ix.i0[1] = s2_0; ix.i0[2] = n_0;
    ix.i1[0] = s1_1; ix.i1[1] = s2_1; ix.i1[2] = n_1;
    ix.i2[0] = s1_2; ix.i2[1] = s2_2; ix.i2[2] = n_2;

    prep_w_k<<<256, 256, 0, stream>>>(Ws0, Wn0, Wt);
    trans_ysg_k<<<TBLK + 291, 256, 0, stream>>>(feat, Wt, ix, yn8, ysr);

    gather_all_k<<<NB, 320, 0, stream>>>((const uint*)ysr, (const uint*)yn8, ix, mg1, g0);

    final_fused_k<<<NB / 8, 256, 0, stream>>>(g0, mg1, Ws1, Wn1, u1, u2, un);

    aff_neg_k<<<BB, 256, 0, stream>>>(u1, u2, un, aff, neg, part);
    loss_final_k<<<1, 256, 0, stream>>>(part, loss);
}